// Round 13
// baseline (177.764 us; speedup 1.0000x reference)
//
#include <hip/hip_runtime.h>
#include <hip/hip_bf16.h>
#include <math.h>

#define BB 8
#define NN 2048
#define KK 30
#define NF 128
#define EF 128
#define NPE 16
#define NRBF 16
#define MAXREL 32

#define V_OUT_SZ   (BB*NN*NF)
#define E_OUT_OFF  (V_OUT_SZ)
#define E_OUT_SZ   (BB*NN*KK*EF)
#define EIDX_OUT_OFF (E_OUT_OFF + E_OUT_SZ)

// workspace byte offsets
#define WS_EIDX_OFF 0                       // int[B*N*K]
#define WS_DNB_OFF  1966080                 // float[B*N*K]
#define WS_O_OFF    3932160                 // float[B*N*9]
#define WS_V6_OFF   4521984                 // float[B*N*6]
#define WS_CA4_OFF  4915200                 // float4[B*N]      (Ca.xyz, mask)
#define WS_W1_OFF   5177344                 // bf16[8192]   L1 frags
#define WS_W2_OFF   5193728                 // bf16[16384]  L2 frags
// end 5226496

typedef __attribute__((ext_vector_type(8))) short bf16x8;
typedef __attribute__((ext_vector_type(4))) float f32x4;
#define MFMA16(a,b,c) __builtin_amdgcn_mfma_f32_16x16x32_bf16(a,b,c,0,0,0)

struct F3 { float x, y, z; };
__device__ inline F3 f3sub(F3 a, F3 b){ return {a.x-b.x, a.y-b.y, a.z-b.z}; }
__device__ inline F3 f3cross(F3 a, F3 b){ return {a.y*b.z - a.z*b.y, a.z*b.x - a.x*b.z, a.x*b.y - a.y*b.x}; }
__device__ inline float f3dot(F3 a, F3 b){ return a.x*b.x + a.y*b.y + a.z*b.z; }
__device__ inline F3 f3norm(F3 v){
    float n = sqrtf(f3dot(v, v));
    float r = 1.0f/(n + 1e-8f);
    return {v.x*r, v.y*r, v.z*r};
}
__device__ inline float sgnf(float x){ return (x>0.f)?1.f:((x<0.f)?-1.f:0.f); }
__device__ inline short f2bf(float f){
    union { __hip_bfloat16 h; short s; } u;
    u.h = __float2bfloat16(f);
    return u.s;
}

// ---------------------------------------------------------------------------
// VALU-only cross-lane min butterflies (f32 value phase + u32 index phase).
// ---------------------------------------------------------------------------
template<int CTRL>
__device__ __forceinline__ float fmin_dpp(float x){
    int xi = __float_as_int(x);
    int yi = __builtin_amdgcn_update_dpp(xi, xi, CTRL, 0xf, 0xf, false);
    return fminf(x, __int_as_float(yi));
}
template<int CTRL>
__device__ __forceinline__ unsigned umin_dpp(unsigned x){
    int yi = __builtin_amdgcn_update_dpp((int)x, (int)x, CTRL, 0xf, 0xf, false);
    return min(x, (unsigned)yi);
}

#if __has_builtin(__builtin_amdgcn_permlane16_swap)
__device__ __forceinline__ float fmin_x16(float x){
    unsigned xb = __float_as_uint(x);
    auto r = __builtin_amdgcn_permlane16_swap(xb, xb, false, false);
    return fminf(x, fminf(__uint_as_float(r[0]), __uint_as_float(r[1])));
}
__device__ __forceinline__ unsigned umin_x16(unsigned x){
    auto r = __builtin_amdgcn_permlane16_swap(x, x, false, false);
    return min(x, min((unsigned)r[0], (unsigned)r[1]));
}
#else
__device__ __forceinline__ float fmin_x16(float x){
    int yi = __builtin_amdgcn_ds_swizzle(__float_as_int(x), 0x401F);
    return fminf(x, __int_as_float(yi));
}
__device__ __forceinline__ unsigned umin_x16(unsigned x){
    int yi = __builtin_amdgcn_ds_swizzle((int)x, 0x401F);
    return min(x, (unsigned)yi);
}
#endif

#if __has_builtin(__builtin_amdgcn_permlane32_swap)
__device__ __forceinline__ float fmin_x32(float x){
    unsigned xb = __float_as_uint(x);
    auto r = __builtin_amdgcn_permlane32_swap(xb, xb, false, false);
    return fminf(x, fminf(__uint_as_float(r[0]), __uint_as_float(r[1])));
}
__device__ __forceinline__ unsigned umin_x32(unsigned x){
    auto r = __builtin_amdgcn_permlane32_swap(x, x, false, false);
    return min(x, min((unsigned)r[0], (unsigned)r[1]));
}
#else
__device__ __forceinline__ float fmin_x32(float x){
    return fminf(x, __shfl_xor(x, 32, 64));
}
__device__ __forceinline__ unsigned umin_x32(unsigned x){
    return min(x, (unsigned)__shfl_xor((int)x, 32, 64));
}
#endif

__device__ __forceinline__ float wave_fmin(float x){
    x = fmin_dpp<0xB1>(x);    // quad_perm xor 1
    x = fmin_dpp<0x4E>(x);    // quad_perm xor 2
    x = fmin_dpp<0x124>(x);   // row_ror:4
    x = fmin_dpp<0x128>(x);   // row_ror:8
    x = fmin_x16(x);
    x = fmin_x32(x);
    return x;                 // all 64 lanes hold the min
}
__device__ __forceinline__ unsigned wave_umin(unsigned x){
    x = umin_dpp<0xB1>(x);
    x = umin_dpp<0x4E>(x);
    x = umin_dpp<0x124>(x);
    x = umin_dpp<0x128>(x);
    x = umin_x16(x);
    x = umin_x32(x);
    return x;
}

// ---------------------------------------------------------------------------
// Kernel P: pre-convert edge-MLP weights into bf16 MFMA-fragment order.
// COLUMN PERMUTATION (new): fragment f8 = wn*4+nf covers actual output cols
// wn*64 + 4*c + nf (c = intra-fragment col 0..15), so that in the edge kernel
// each lane owns 4 CONSECUTIVE output columns (4*lr .. 4*lr+3) -> float4
// stores. k (input-feature) ordering unchanged.
// ---------------------------------------------------------------------------
__global__ void prep_kernel(const float* __restrict__ elw,
                            const float* __restrict__ eew,
                            __hip_bfloat16* __restrict__ w1,
                            __hip_bfloat16* __restrict__ w2)
{
    int i = blockIdx.x*256 + threadIdx.x;
    if (i < 8192) {
        int j = i & 7, lane = (i>>3)&63, ks = (i>>9)&1, f8 = i>>10;
        int k = ks*32 + (lane>>4)*8 + j;
        int col = (f8>>2)*64 + 4*(lane&15) + (f8&3);
        float v = (k < 39) ? elw[k*128 + col] : 0.f;
        w1[i] = __float2bfloat16(v);
    } else if (i < 8192 + 16384) {
        int i2 = i - 8192;
        int j = i2 & 7, lane = (i2>>3)&63, ks = (i2>>9)&3, f8 = i2>>11;
        int k = ks*32 + (lane>>4)*8 + j;
        int col = (f8>>2)*64 + 4*(lane&15) + (f8&3);
        w2[i2] = __float2bfloat16(eew[k*128 + col]);
    }
}

// ---------------------------------------------------------------------------
// Kernel A: per-node geometry -> V6 (dihedral 6), O (9), packed Ca4 (xyz+mask)
// ---------------------------------------------------------------------------
__global__ void geom_kernel(const float* __restrict__ X,
                            const float* __restrict__ mask,
                            float* __restrict__ wsO, float* __restrict__ wsV6,
                            float4* __restrict__ wsCa4)
{
    int ng = blockIdx.x * blockDim.x + threadIdx.x;
    if (ng >= BB*NN) return;
    int b = ng / NN, n = ng % NN;
    const float* Xb = X + (size_t)b * NN * 12;

    {
        const float* cp = X + (size_t)ng*12 + 3;
        wsCa4[ng] = make_float4(cp[0], cp[1], cp[2], mask[ng]);
    }

    int k0 = 3*n - 1;
    F3 P[6];
    #pragma unroll
    for (int t = 0; t < 6; ++t) {
        int m = k0 + t;
        if (m < 0) m = 0;
        if (m > 3*NN-1) m = 3*NN-1;
        int r = m / 3, a = m % 3;
        const float* p = Xb + ((size_t)r*4 + a)*3;
        P[t] = {p[0], p[1], p[2]};
    }
    F3 U[5];
    #pragma unroll
    for (int t = 0; t < 5; ++t) U[t] = f3norm(f3sub(P[t+1], P[t]));

    float Dang[3];
    #pragma unroll
    for (int t = 0; t < 3; ++t) {
        int k = k0 + t;
        if (k < 0 || k > 3*NN-4) { Dang[t] = 0.f; continue; }
        F3 u2 = U[t], u1 = U[t+1], u0 = U[t+2];
        F3 n2 = f3norm(f3cross(u2, u1));
        F3 n1 = f3norm(f3cross(u1, u0));
        float cosD = f3dot(n2, n1);
        cosD = fminf(fmaxf(cosD, -1.f + 1e-7f), 1.f - 1e-7f);
        float s = f3dot(u2, n1);
        Dang[t] = sgnf(s) * acosf(cosD);
    }
    float* v6 = wsV6 + (size_t)ng * 6;
    v6[0] = cosf(Dang[0]); v6[1] = cosf(Dang[1]); v6[2] = cosf(Dang[2]);
    v6[3] = sinf(Dang[0]); v6[4] = sinf(Dang[1]); v6[5] = sinf(Dang[2]);

    float* o = wsO + (size_t)ng * 9;
    if (n >= 1 && n <= NN-3) {
        const float* cb = X + (size_t)b * NN * 12 + 3;
        F3 c0 = {cb[(size_t)(n-1)*12+0], cb[(size_t)(n-1)*12+1], cb[(size_t)(n-1)*12+2]};
        F3 c1 = {cb[(size_t)(n  )*12+0], cb[(size_t)(n  )*12+1], cb[(size_t)(n  )*12+2]};
        F3 c2 = {cb[(size_t)(n+1)*12+0], cb[(size_t)(n+1)*12+1], cb[(size_t)(n+1)*12+2]};
        F3 u2 = f3norm(f3sub(c1, c0));
        F3 u1 = f3norm(f3sub(c2, c1));
        F3 n2 = f3norm(f3cross(u2, u1));
        F3 o1 = f3norm(f3sub(u2, u1));
        F3 r2 = f3cross(o1, n2);
        o[0]=o1.x; o[1]=o1.y; o[2]=o1.z;
        o[3]=n2.x; o[4]=n2.y; o[5]=n2.z;
        o[6]=r2.x; o[7]=r2.y; o[8]=r2.z;
    } else {
        #pragma unroll
        for (int m = 0; m < 9; ++m) o[m] = 0.f;
    }
}

// ---------------------------------------------------------------------------
// Kernel B: top-K, register-queue (best-known build, 82us). FROZEN.
// ---------------------------------------------------------------------------
#define KEMPTY 8.9884656743115795e+307   // 0x7FE0...0: d_bits=huge, j=0

__device__ __forceinline__ double make_key(float d, int j){
    unsigned long long k =
        ((unsigned long long)__float_as_uint(d) << 32) | (unsigned)j;
    return __longlong_as_double((long long)k);
}

__device__ __forceinline__ void ins3(double& q0, double& q1, double& q2, double k){
    double k2 = fmin(k, q2);          // drop max(k, q2)
    double t1 = fmin(q1, k2); q2 = fmax(q1, k2);
    double t0 = fmin(q0, t1); q1 = fmax(q0, t1);
    q0 = t0;
}

__global__ __launch_bounds__(256, 4) void topk_kernel(
    const float4* __restrict__ wsCa4,
    int* __restrict__ wsEidx, float* __restrict__ wsDnb,
    float* __restrict__ outEidxF)
{
    const int wave = threadIdx.x >> 6, lane = threadIdx.x & 63;
    const int row = blockIdx.x*4 + wave;
    const int b = row >> 11, i = row & (NN-1);

    const float4* cb = wsCa4 + ((size_t)b << 11);
    float4 ci = cb[i];
    float mi = ci.w;

    float dloc[32];
    double q0 = KEMPTY, q1 = KEMPTY, q2 = KEMPTY;
    #pragma unroll
    for (int s = 0; s < 32; ++s) {
        int j = s*64 + lane;
        float4 cj = cb[j];
        float dx = __fsub_rn(ci.x, cj.x);
        float dy = __fsub_rn(ci.y, cj.y);
        float dz = __fsub_rn(ci.z, cj.z);
        float d2 = __fadd_rn(__fadd_rn(__fadd_rn(__fmul_rn(dx,dx),
                                                 __fmul_rn(dy,dy)),
                                       __fmul_rn(dz,dz)), 1e-6f);
        float d = sqrtf(d2);
        d = __fadd_rn(d, __fmul_rn(__fsub_rn(1.0f, __fmul_rn(mi, cj.w)), 10000.0f));
        dloc[s] = d;
        ins3(q0, q1, q2, make_key(d, j));
    }

    double res = KEMPTY;
    #pragma unroll 1
    for (int k = 0; k < KK; ++k) {
        unsigned long long q0b = (unsigned long long)__double_as_longlong(q0);
        float    hd = __uint_as_float((unsigned)(q0b >> 32));
        unsigned hj = (unsigned)q0b;

        float dmin = wave_fmin(hd);
        unsigned cand = (hd == dmin) ? hj : 0xFFFFFFFFu;
        unsigned jmin = wave_umin(cand);

        if (lane == k)
            res = __longlong_as_double((long long)(
                ((unsigned long long)__float_as_uint(dmin) << 32) | jmin));

        if (hd == dmin && hj == jmin) {   // exactly one lane (j unique)
            q0 = q1; q1 = q2; q2 = KEMPTY;
            if (__double_as_longlong(q0) == __double_as_longlong(KEMPTY)) {
                // refill with 3 smallest keys > g (monotone pops -> exact)
                double g = __longlong_as_double((long long)(
                    ((unsigned long long)__float_as_uint(dmin) << 32) | jmin));
                #pragma unroll
                for (int s = 0; s < 32; ++s) {
                    double kk = make_key(dloc[s], s*64 + lane);
                    if (!(kk > g)) kk = KEMPTY;
                    ins3(q0, q1, q2, kk);
                }
            }
        }
    }

    if (lane < KK) {
        const size_t rb = (size_t)row * KK;
        unsigned long long gk = (unsigned long long)__double_as_longlong(res);
        int j = (int)(unsigned)gk;
        float dwin = __uint_as_float((unsigned)(gk >> 32));
        wsEidx[rb + lane] = j;
        wsDnb[rb + lane]  = dwin;
        outEidxF[rb + lane] = (float)j;
    }
}

// ---------------------------------------------------------------------------
// Kernel C: node path (unchanged)
// ---------------------------------------------------------------------------
__global__ __launch_bounds__(128) void node_kernel(
    const float* __restrict__ wsV6,
    const float* __restrict__ nlw, const float* __restrict__ nlb,
    const float* __restrict__ new_, const float* __restrict__ neb,
    const float* __restrict__ nng, const float* __restrict__ nnb,
    float* __restrict__ outV)
{
    int f = threadIdx.x;
    __shared__ float h1[128];
    __shared__ float red[2][2];

    float w2[128];
    #pragma unroll
    for (int c = 0; c < 128; ++c) w2[c] = new_[c*128 + f];
    float w1[6];
    #pragma unroll
    for (int c = 0; c < 6; ++c) w1[c] = nlw[c*128 + f];
    float b1v = nlb[f], b2v = neb[f], gv = nng[f], bv = nnb[f];

    for (int gi = 0; gi < 8; ++gi) {
        int row = blockIdx.x*8 + gi;
        float acc = b1v;
        #pragma unroll
        for (int c = 0; c < 6; ++c) acc = fmaf(wsV6[(size_t)row*6 + c], w1[c], acc);
        h1[f] = acc;
        __syncthreads();

        float a2 = b2v;
        #pragma unroll
        for (int c4 = 0; c4 < 32; ++c4) {
            float4 v = *(const float4*)&h1[c4*4];
            a2 = fmaf(v.x, w2[c4*4+0], a2);
            a2 = fmaf(v.y, w2[c4*4+1], a2);
            a2 = fmaf(v.z, w2[c4*4+2], a2);
            a2 = fmaf(v.w, w2[c4*4+3], a2);
        }
        float s = a2, ss = a2*a2;
        #pragma unroll
        for (int off = 32; off; off >>= 1) {
            s  += __shfl_xor(s,  off, 64);
            ss += __shfl_xor(ss, off, 64);
        }
        int wig = f >> 6;
        if ((f & 63) == 0) { red[wig][0] = s; red[wig][1] = ss; }
        __syncthreads();
        float S = red[0][0] + red[1][0], SS = red[0][1] + red[1][1];
        float mu = S * (1.f/128.f);
        float var = SS * (1.f/128.f) - mu*mu;
        float inv = rsqrtf(var + 1e-5f);
        outV[(size_t)row*128 + f] = (a2 - mu)*inv*gv + bv;
        __syncthreads();
    }
}

// ---------------------------------------------------------------------------
// Kernel D: edge MFMA. Column-permuted W fragments (lane owns 4 consecutive
// output cols: wn*64 + 4*lr + nf) -> h1t writes are ds_write_b64 (short4)
// and the LN epilogue stores are global_store_dwordx4 (float4), 4x fewer
// store instructions with 256B-contiguous coverage per 16-lane group.
// ---------------------------------------------------------------------------
__global__ __launch_bounds__(256, 4) void edge_mfma_kernel(
    const float4* __restrict__ wsCa4,
    const int* __restrict__ ridx, const int* __restrict__ chain,
    const int* __restrict__ wsEidx, const float* __restrict__ wsDnb,
    const float* __restrict__ wsO,
    const float* __restrict__ pe_w, const float* __restrict__ pe_b,
    const __hip_bfloat16* __restrict__ wsW1, const __hip_bfloat16* __restrict__ wsW2,
    const float* __restrict__ elb, const float* __restrict__ eeb,
    const float* __restrict__ lng, const float* __restrict__ lnb,
    float* __restrict__ outE)
{
    __shared__ char smem[64*72*2 + 64*136*2];
    short* Ef  = (short*)smem;
    short* h1t = (short*)(smem + 64*72*2);
    float* redS  = (float*)smem;
    float* redSS = (float*)(smem + 512);

    const int tid  = threadIdx.x;
    const int wave = tid >> 6, lane = tid & 63;
    const int wm = wave >> 1, wn = wave & 1;
    const int lr = lane & 15, lk = lane >> 4;

    // permuted column ownership: this lane's 4 cols are colbase + nf (nf=0..3)
    const int colbase = wn*64 + 4*lr;

    float b1v[4], b2v[4], gv[4], bv[4];
    #pragma unroll
    for (int nf = 0; nf < 4; ++nf) {
        int col = colbase + nf;
        b1v[nf] = elb[col]; b2v[nf] = eeb[col];
        gv[nf]  = lng[col]; bv[nf]  = lnb[col];
    }

    for (int idx = tid; idx < 64*25; idx += 256) {
        int r = idx / 25, c = 39 + idx % 25;
        Ef[r*72 + c] = 0;
    }

    const int E0 = blockIdx.x * 64;

    if (wave == 0) {
        int ge = E0 + lane;
        int row = ge / KK;
        int b = row >> 11;
        int j = wsEidx[ge];
        float oi[9], oj[9];
        #pragma unroll
        for (int m = 0; m < 9; ++m) {
            oi[m] = wsO[(size_t)row*9 + m];
            oj[m] = wsO[((size_t)(b*NN) + j)*9 + m];
        }
        float4 ci = wsCa4[row];
        float4 cj = wsCa4[(size_t)b*NN + j];
        float dx = cj.x-ci.x, dy = cj.y-ci.y, dz = cj.z-ci.z;
        float t0 = oi[0]*dx + oi[1]*dy + oi[2]*dz;
        float t1 = oi[3]*dx + oi[4]*dy + oi[5]*dz;
        float t2 = oi[6]*dx + oi[7]*dy + oi[8]*dz;
        float nr = sqrtf(t0*t0 + t1*t1 + t2*t2);
        float iv = 1.f/(nr + 1e-8f);
        short* ef = &Ef[lane*72];
        ef[32] = f2bf(t0*iv); ef[33] = f2bf(t1*iv); ef[34] = f2bf(t2*iv);
        float R00 = oi[0]*oj[0]+oi[3]*oj[3]+oi[6]*oj[6];
        float R01 = oi[0]*oj[1]+oi[3]*oj[4]+oi[6]*oj[7];
        float R02 = oi[0]*oj[2]+oi[3]*oj[5]+oi[6]*oj[8];
        float R10 = oi[1]*oj[0]+oi[4]*oj[3]+oi[7]*oj[6];
        float R11 = oi[1]*oj[1]+oi[4]*oj[4]+oi[7]*oj[7];
        float R12 = oi[1]*oj[2]+oi[4]*oj[5]+oi[7]*oj[8];
        float R20 = oi[2]*oj[0]+oi[5]*oj[3]+oi[8]*oj[6];
        float R21 = oi[2]*oj[1]+oi[5]*oj[4]+oi[8]*oj[7];
        float R22 = oi[2]*oj[2]+oi[5]*oj[5]+oi[8]*oj[8];
        float mx = 0.5f*sqrtf(fabsf(1.f + R00 - R11 - R22));
        float my = 0.5f*sqrtf(fabsf(1.f - R00 + R11 - R22));
        float mz = 0.5f*sqrtf(fabsf(1.f - R00 - R11 + R22));
        float qx = sgnf(R21 - R12)*mx;
        float qy = sgnf(R02 - R20)*my;
        float qz = sgnf(R10 - R01)*mz;
        float qw = 0.5f*sqrtf(fmaxf(0.f, 1.f + R00 + R11 + R22));
        float qn = sqrtf(qx*qx + qy*qy + qz*qz + qw*qw);
        float qi = 1.f/(qn + 1e-8f);
        ef[35] = f2bf(qx*qi); ef[36] = f2bf(qy*qi);
        ef[37] = f2bf(qz*qi); ef[38] = f2bf(qw*qi);
    } else if (wave == 1) {
        int ge = E0 + lane;
        float dnb = wsDnb[ge];
        short* ef = &Ef[lane*72 + 16];
        #pragma unroll
        for (int m = 0; m < 16; ++m) {
            float mu = 2.f + (20.f/15.f)*(float)m;
            float z = (dnb - mu) * 0.8f;
            ef[m] = f2bf(expf(-z*z));
        }
    } else if (wave == 2) {
        int ge = E0 + lane;
        int row = ge / KK;
        int b = row >> 11;
        int j = wsEidx[ge];
        int ri = ridx[row], rj = ridx[b*NN + j];
        int ch = (chain[row] == chain[b*NN + j]) ? 1 : 0;
        int dd = min(max(ri - rj + MAXREL, 0), 2*MAXREL);
        dd = ch ? dd : (2*MAXREL + 1);
        short* ef = &Ef[lane*72];
        #pragma unroll
        for (int m = 0; m < 16; ++m) ef[m] = f2bf(pe_w[dd*16 + m] + pe_b[m]);
    }
    __syncthreads();

    const bf16x8* W1f = (const bf16x8*)wsW1;
    const bf16x8* W2f = (const bf16x8*)wsW2;

    f32x4 acc[2][4];
    #pragma unroll
    for (int mf = 0; mf < 2; ++mf)
        #pragma unroll
        for (int nf = 0; nf < 4; ++nf)
            acc[mf][nf] = (f32x4){0.f, 0.f, 0.f, 0.f};
    #pragma unroll
    for (int ks = 0; ks < 2; ++ks) {
        bf16x8 a0 = *(const bf16x8*)&Ef[(wm*32      + lr)*72 + ks*32 + lk*8];
        bf16x8 a1 = *(const bf16x8*)&Ef[(wm*32 + 16 + lr)*72 + ks*32 + lk*8];
        #pragma unroll
        for (int nf = 0; nf < 4; ++nf) {
            bf16x8 Bf = W1f[((wn*4 + nf)*2 + ks)*64 + lane];
            acc[0][nf] = MFMA16(a0, Bf, acc[0][nf]);
            acc[1][nf] = MFMA16(a1, Bf, acc[1][nf]);
        }
    }
    // h1 store: lane owns cols colbase..colbase+3 -> short4 (b64) writes,
    // h1t remains in LINEAR feature order (value for feature c at col c).
    #pragma unroll
    for (int mf = 0; mf < 2; ++mf)
        #pragma unroll
        for (int r = 0; r < 4; ++r) {
            int row = wm*32 + mf*16 + lk*4 + r;
            short4 h4;
            h4.x = f2bf(acc[mf][0][r] + b1v[0]);
            h4.y = f2bf(acc[mf][1][r] + b1v[1]);
            h4.z = f2bf(acc[mf][2][r] + b1v[2]);
            h4.w = f2bf(acc[mf][3][r] + b1v[3]);
            *(short4*)&h1t[row*136 + colbase] = h4;
        }
    __syncthreads();

    f32x4 acc2[2][4];
    #pragma unroll
    for (int mf = 0; mf < 2; ++mf)
        #pragma unroll
        for (int nf = 0; nf < 4; ++nf)
            acc2[mf][nf] = (f32x4){0.f, 0.f, 0.f, 0.f};
    #pragma unroll
    for (int ks = 0; ks < 4; ++ks) {
        bf16x8 a0 = *(const bf16x8*)&h1t[(wm*32      + lr)*136 + ks*32 + lk*8];
        bf16x8 a1 = *(const bf16x8*)&h1t[(wm*32 + 16 + lr)*136 + ks*32 + lk*8];
        #pragma unroll
        for (int nf = 0; nf < 4; ++nf) {
            bf16x8 Bf = W2f[((wn*4 + nf)*4 + ks)*64 + lane];
            acc2[0][nf] = MFMA16(a0, Bf, acc2[0][nf]);
            acc2[1][nf] = MFMA16(a1, Bf, acc2[1][nf]);
        }
    }
    #pragma unroll
    for (int mf = 0; mf < 2; ++mf)
        #pragma unroll
        for (int nf = 0; nf < 4; ++nf)
            #pragma unroll
            for (int r = 0; r < 4; ++r)
                acc2[mf][nf][r] += b2v[nf];

    #pragma unroll
    for (int mf = 0; mf < 2; ++mf) {
        #pragma unroll
        for (int r = 0; r < 4; ++r) {
            float v0 = acc2[mf][0][r], v1 = acc2[mf][1][r];
            float v2 = acc2[mf][2][r], v3 = acc2[mf][3][r];
            float s = v0 + v1 + v2 + v3;
            float q = v0*v0 + v1*v1 + v2*v2 + v3*v3;
            #pragma unroll
            for (int off = 1; off < 16; off <<= 1) {
                s += __shfl_xor(s, off, 64);
                q += __shfl_xor(q, off, 64);
            }
            if (lr == 0) {
                int row = wm*32 + mf*16 + lk*4 + r;
                redS[row*2 + wn] = s; redSS[row*2 + wn] = q;
            }
        }
    }
    __syncthreads();

    // LN + store: float4 per (mf, r) -> lanes lr=0..15 cover 256B contiguous.
    const size_t obase = (size_t)E0 * 128;
    #pragma unroll
    for (int mf = 0; mf < 2; ++mf) {
        #pragma unroll
        for (int r = 0; r < 4; ++r) {
            int row = wm*32 + mf*16 + lk*4 + r;
            float S = redS[row*2 + 0] + redS[row*2 + 1];
            float Q = redSS[row*2 + 0] + redSS[row*2 + 1];
            float mu = S * (1.f/128.f);
            float var = Q * (1.f/128.f) - mu*mu;
            float inv = rsqrtf(var + 1e-5f);
            float4 o4;
            o4.x = (acc2[mf][0][r] - mu)*inv*gv[0] + bv[0];
            o4.y = (acc2[mf][1][r] - mu)*inv*gv[1] + bv[1];
            o4.z = (acc2[mf][2][r] - mu)*inv*gv[2] + bv[2];
            o4.w = (acc2[mf][3][r] - mu)*inv*gv[3] + bv[3];
            *(float4*)&outE[obase + (size_t)row*128 + colbase] = o4;
        }
    }
}

// ---------------------------------------------------------------------------
extern "C" void kernel_launch(void* const* d_in, const int* in_sizes, int n_in,
                              void* d_out, int out_size, void* d_ws, size_t ws_size,
                              hipStream_t stream)
{
    const float* X     = (const float*)d_in[0];
    const float* mask  = (const float*)d_in[1];
    const int*   ridx  = (const int*)  d_in[2];
    const int*   chain = (const int*)  d_in[3];
    const float* pe_w  = (const float*)d_in[4];
    const float* pe_b  = (const float*)d_in[5];
    const float* nlw   = (const float*)d_in[6];
    const float* nlb   = (const float*)d_in[7];
    const float* new_  = (const float*)d_in[8];
    const float* neb   = (const float*)d_in[9];
    const float* elw   = (const float*)d_in[10];
    const float* elb   = (const float*)d_in[11];
    const float* eew   = (const float*)d_in[12];
    const float* eeb   = (const float*)d_in[13];
    const float* nng   = (const float*)d_in[14];
    const float* nnb   = (const float*)d_in[15];
    const float* neg_  = (const float*)d_in[16];
    const float* neb_  = (const float*)d_in[17];

    float* out = (float*)d_out;
    char*  ws  = (char*)d_ws;
    int*    wsEidx = (int*)   (ws + WS_EIDX_OFF);
    float*  wsDnb  = (float*) (ws + WS_DNB_OFF);
    float*  wsO    = (float*) (ws + WS_O_OFF);
    float*  wsV6   = (float*) (ws + WS_V6_OFF);
    float4* wsCa4  = (float4*)(ws + WS_CA4_OFF);
    __hip_bfloat16* wsW1 = (__hip_bfloat16*)(ws + WS_W1_OFF);
    __hip_bfloat16* wsW2 = (__hip_bfloat16*)(ws + WS_W2_OFF);

    prep_kernel<<<96, 256, 0, stream>>>(elw, eew, wsW1, wsW2);
    geom_kernel<<<(BB*NN + 255)/256, 256, 0, stream>>>(X, mask, wsO, wsV6, wsCa4);
    topk_kernel<<<BB*NN/4, 256, 0, stream>>>(wsCa4, wsEidx, wsDnb, out + EIDX_OUT_OFF);
    node_kernel<<<BB*NN/8, 128, 0, stream>>>(wsV6, nlw, nlb, new_, neb, nng, nnb, out);
    edge_mfma_kernel<<<BB*NN*KK/64, 256, 0, stream>>>(wsCa4, ridx, chain, wsEidx, wsDnb, wsO,
                                                      pe_w, pe_b, wsW1, wsW2,
                                                      elb, eeb, neg_, neb_, out + E_OUT_OFF);
}

// Round 14
// 173.130 us; speedup vs baseline: 1.0268x; 1.0268x over previous
//
#include <hip/hip_runtime.h>
#include <hip/hip_bf16.h>
#include <math.h>

#define BB 8
#define NN 2048
#define KK 30
#define NF 128
#define EF 128
#define NPE 16
#define NRBF 16
#define MAXREL 32

#define V_OUT_SZ   (BB*NN*NF)
#define E_OUT_OFF  (V_OUT_SZ)
#define E_OUT_SZ   (BB*NN*KK*EF)
#define EIDX_OUT_OFF (E_OUT_OFF + E_OUT_SZ)

// workspace byte offsets
#define WS_EIDX_OFF 0                       // int[B*N*K]
#define WS_DNB_OFF  1966080                 // float[B*N*K]
#define WS_O_OFF    3932160                 // float[B*N*9]
#define WS_V6_OFF   4521984                 // float[B*N*6]
#define WS_CA4_OFF  4915200                 // float4[B*N]      (Ca.xyz, mask)
#define WS_W1_OFF   5177344                 // bf16[8192]   L1 frags
#define WS_W2_OFF   5193728                 // bf16[16384]  L2 frags
// end 5226496

typedef __attribute__((ext_vector_type(8))) short bf16x8;
typedef __attribute__((ext_vector_type(4))) float f32x4;
#define MFMA16(a,b,c) __builtin_amdgcn_mfma_f32_16x16x32_bf16(a,b,c,0,0,0)

struct F3 { float x, y, z; };
__device__ inline F3 f3sub(F3 a, F3 b){ return {a.x-b.x, a.y-b.y, a.z-b.z}; }
__device__ inline F3 f3cross(F3 a, F3 b){ return {a.y*b.z - a.z*b.y, a.z*b.x - a.x*b.z, a.x*b.y - a.y*b.x}; }
__device__ inline float f3dot(F3 a, F3 b){ return a.x*b.x + a.y*b.y + a.z*b.z; }
__device__ inline F3 f3norm(F3 v){
    float n = sqrtf(f3dot(v, v));
    float r = 1.0f/(n + 1e-8f);
    return {v.x*r, v.y*r, v.z*r};
}
__device__ inline float sgnf(float x){ return (x>0.f)?1.f:((x<0.f)?-1.f:0.f); }
__device__ inline short f2bf(float f){
    union { __hip_bfloat16 h; short s; } u;
    u.h = __float2bfloat16(f);
    return u.s;
}

// ---------------------------------------------------------------------------
// VALU-only cross-lane min butterflies (f32 value phase + u32 index phase).
// DPP covers xor1/2 + ror4/8 within 16-lane rows; gfx950 permlane16/32_swap
// covers the row/half exchange. Fallbacks guarded by __has_builtin.
// ---------------------------------------------------------------------------
template<int CTRL>
__device__ __forceinline__ float fmin_dpp(float x){
    int xi = __float_as_int(x);
    int yi = __builtin_amdgcn_update_dpp(xi, xi, CTRL, 0xf, 0xf, false);
    return fminf(x, __int_as_float(yi));
}
template<int CTRL>
__device__ __forceinline__ unsigned umin_dpp(unsigned x){
    int yi = __builtin_amdgcn_update_dpp((int)x, (int)x, CTRL, 0xf, 0xf, false);
    return min(x, (unsigned)yi);
}

#if __has_builtin(__builtin_amdgcn_permlane16_swap)
__device__ __forceinline__ float fmin_x16(float x){
    unsigned xb = __float_as_uint(x);
    auto r = __builtin_amdgcn_permlane16_swap(xb, xb, false, false);
    return fminf(x, fminf(__uint_as_float(r[0]), __uint_as_float(r[1])));
}
__device__ __forceinline__ unsigned umin_x16(unsigned x){
    auto r = __builtin_amdgcn_permlane16_swap(x, x, false, false);
    return min(x, min((unsigned)r[0], (unsigned)r[1]));
}
#else
__device__ __forceinline__ float fmin_x16(float x){
    int yi = __builtin_amdgcn_ds_swizzle(__float_as_int(x), 0x401F);
    return fminf(x, __int_as_float(yi));
}
__device__ __forceinline__ unsigned umin_x16(unsigned x){
    int yi = __builtin_amdgcn_ds_swizzle((int)x, 0x401F);
    return min(x, (unsigned)yi);
}
#endif

#if __has_builtin(__builtin_amdgcn_permlane32_swap)
__device__ __forceinline__ float fmin_x32(float x){
    unsigned xb = __float_as_uint(x);
    auto r = __builtin_amdgcn_permlane32_swap(xb, xb, false, false);
    return fminf(x, fminf(__uint_as_float(r[0]), __uint_as_float(r[1])));
}
__device__ __forceinline__ unsigned umin_x32(unsigned x){
    auto r = __builtin_amdgcn_permlane32_swap(x, x, false, false);
    return min(x, min((unsigned)r[0], (unsigned)r[1]));
}
#else
__device__ __forceinline__ float fmin_x32(float x){
    return fminf(x, __shfl_xor(x, 32, 64));
}
__device__ __forceinline__ unsigned umin_x32(unsigned x){
    return min(x, (unsigned)__shfl_xor((int)x, 32, 64));
}
#endif

__device__ __forceinline__ float wave_fmin(float x){
    x = fmin_dpp<0xB1>(x);    // quad_perm xor 1
    x = fmin_dpp<0x4E>(x);    // quad_perm xor 2
    x = fmin_dpp<0x124>(x);   // row_ror:4
    x = fmin_dpp<0x128>(x);   // row_ror:8
    x = fmin_x16(x);
    x = fmin_x32(x);
    return x;                 // all 64 lanes hold the min
}
__device__ __forceinline__ unsigned wave_umin(unsigned x){
    x = umin_dpp<0xB1>(x);
    x = umin_dpp<0x4E>(x);
    x = umin_dpp<0x124>(x);
    x = umin_dpp<0x128>(x);
    x = umin_x16(x);
    x = umin_x32(x);
    return x;
}

// ---------------------------------------------------------------------------
// Kernel P: pre-convert edge-MLP weights into bf16 MFMA-fragment order.
// ---------------------------------------------------------------------------
__global__ void prep_kernel(const float* __restrict__ elw,
                            const float* __restrict__ eew,
                            __hip_bfloat16* __restrict__ w1,
                            __hip_bfloat16* __restrict__ w2)
{
    int i = blockIdx.x*256 + threadIdx.x;
    if (i < 8192) {
        int j = i & 7, lane = (i>>3)&63, ks = (i>>9)&1, nf = i>>10;
        int k = ks*32 + (lane>>4)*8 + j;
        int col = nf*16 + (lane&15);
        float v = (k < 39) ? elw[k*128 + col] : 0.f;
        w1[i] = __float2bfloat16(v);
    } else if (i < 8192 + 16384) {
        int i2 = i - 8192;
        int j = i2 & 7, lane = (i2>>3)&63, ks = (i2>>9)&3, nf = i2>>11;
        int k = ks*32 + (lane>>4)*8 + j;
        int col = nf*16 + (lane&15);
        w2[i2] = __float2bfloat16(eew[k*128 + col]);
    }
}

// ---------------------------------------------------------------------------
// Kernel A: per-node geometry -> V6 (dihedral 6), O (9), packed Ca4 (xyz+mask)
// ---------------------------------------------------------------------------
__global__ void geom_kernel(const float* __restrict__ X,
                            const float* __restrict__ mask,
                            float* __restrict__ wsO, float* __restrict__ wsV6,
                            float4* __restrict__ wsCa4)
{
    int ng = blockIdx.x * blockDim.x + threadIdx.x;
    if (ng >= BB*NN) return;
    int b = ng / NN, n = ng % NN;
    const float* Xb = X + (size_t)b * NN * 12;

    {
        const float* cp = X + (size_t)ng*12 + 3;
        wsCa4[ng] = make_float4(cp[0], cp[1], cp[2], mask[ng]);
    }

    int k0 = 3*n - 1;
    F3 P[6];
    #pragma unroll
    for (int t = 0; t < 6; ++t) {
        int m = k0 + t;
        if (m < 0) m = 0;
        if (m > 3*NN-1) m = 3*NN-1;
        int r = m / 3, a = m % 3;
        const float* p = Xb + ((size_t)r*4 + a)*3;
        P[t] = {p[0], p[1], p[2]};
    }
    F3 U[5];
    #pragma unroll
    for (int t = 0; t < 5; ++t) U[t] = f3norm(f3sub(P[t+1], P[t]));

    float Dang[3];
    #pragma unroll
    for (int t = 0; t < 3; ++t) {
        int k = k0 + t;
        if (k < 0 || k > 3*NN-4) { Dang[t] = 0.f; continue; }
        F3 u2 = U[t], u1 = U[t+1], u0 = U[t+2];
        F3 n2 = f3norm(f3cross(u2, u1));
        F3 n1 = f3norm(f3cross(u1, u0));
        float cosD = f3dot(n2, n1);
        cosD = fminf(fmaxf(cosD, -1.f + 1e-7f), 1.f - 1e-7f);
        float s = f3dot(u2, n1);
        Dang[t] = sgnf(s) * acosf(cosD);
    }
    float* v6 = wsV6 + (size_t)ng * 6;
    v6[0] = cosf(Dang[0]); v6[1] = cosf(Dang[1]); v6[2] = cosf(Dang[2]);
    v6[3] = sinf(Dang[0]); v6[4] = sinf(Dang[1]); v6[5] = sinf(Dang[2]);

    float* o = wsO + (size_t)ng * 9;
    if (n >= 1 && n <= NN-3) {
        const float* cb = X + (size_t)b * NN * 12 + 3;
        F3 c0 = {cb[(size_t)(n-1)*12+0], cb[(size_t)(n-1)*12+1], cb[(size_t)(n-1)*12+2]};
        F3 c1 = {cb[(size_t)(n  )*12+0], cb[(size_t)(n  )*12+1], cb[(size_t)(n  )*12+2]};
        F3 c2 = {cb[(size_t)(n+1)*12+0], cb[(size_t)(n+1)*12+1], cb[(size_t)(n+1)*12+2]};
        F3 u2 = f3norm(f3sub(c1, c0));
        F3 u1 = f3norm(f3sub(c2, c1));
        F3 n2 = f3norm(f3cross(u2, u1));
        F3 o1 = f3norm(f3sub(u2, u1));
        F3 r2 = f3cross(o1, n2);
        o[0]=o1.x; o[1]=o1.y; o[2]=o1.z;
        o[3]=n2.x; o[4]=n2.y; o[5]=n2.z;
        o[6]=r2.x; o[7]=r2.y; o[8]=r2.z;
    } else {
        #pragma unroll
        for (int m = 0; m < 9; ++m) o[m] = 0.f;
    }
}

// ---------------------------------------------------------------------------
// Kernel B: top-K, register-queue (best-known build, 82us). 1 wave/row,
// 4 rows/block, zero LDS. dloc[32] in VGPRs (all dloc loops fully unrolled --
// rule #20). k-loop NOT unrolled (I-cache). Two-phase f32/u32 butterflies
// on the VALU pipe; sorted 3-deep queue of packed (d_bits<<32|j) keys as
// positive doubles (v_min_f64 = exact u64 min). Exact lexicographic (d, j)
// = jax top_k semantics. __f*_rn ops (no contraction) match numpy rounding.
// ---------------------------------------------------------------------------
#define KEMPTY 8.9884656743115795e+307   // 0x7FE0...0: d_bits=huge, j=0

__device__ __forceinline__ double make_key(float d, int j){
    unsigned long long k =
        ((unsigned long long)__float_as_uint(d) << 32) | (unsigned)j;
    return __longlong_as_double((long long)k);
}

__device__ __forceinline__ void ins3(double& q0, double& q1, double& q2, double k){
    double k2 = fmin(k, q2);          // drop max(k, q2)
    double t1 = fmin(q1, k2); q2 = fmax(q1, k2);
    double t0 = fmin(q0, t1); q1 = fmax(q0, t1);
    q0 = t0;
}

__global__ __launch_bounds__(256, 4) void topk_kernel(
    const float4* __restrict__ wsCa4,
    int* __restrict__ wsEidx, float* __restrict__ wsDnb,
    float* __restrict__ outEidxF)
{
    const int wave = threadIdx.x >> 6, lane = threadIdx.x & 63;
    const int row = blockIdx.x*4 + wave;
    const int b = row >> 11, i = row & (NN-1);

    const float4* cb = wsCa4 + ((size_t)b << 11);
    float4 ci = cb[i];
    float mi = ci.w;

    float dloc[32];
    double q0 = KEMPTY, q1 = KEMPTY, q2 = KEMPTY;
    #pragma unroll
    for (int s = 0; s < 32; ++s) {
        int j = s*64 + lane;
        float4 cj = cb[j];
        float dx = __fsub_rn(ci.x, cj.x);
        float dy = __fsub_rn(ci.y, cj.y);
        float dz = __fsub_rn(ci.z, cj.z);
        float d2 = __fadd_rn(__fadd_rn(__fadd_rn(__fmul_rn(dx,dx),
                                                 __fmul_rn(dy,dy)),
                                       __fmul_rn(dz,dz)), 1e-6f);
        float d = sqrtf(d2);
        d = __fadd_rn(d, __fmul_rn(__fsub_rn(1.0f, __fmul_rn(mi, cj.w)), 10000.0f));
        dloc[s] = d;
        ins3(q0, q1, q2, make_key(d, j));
    }

    double res = KEMPTY;
    #pragma unroll 1
    for (int k = 0; k < KK; ++k) {
        unsigned long long q0b = (unsigned long long)__double_as_longlong(q0);
        float    hd = __uint_as_float((unsigned)(q0b >> 32));
        unsigned hj = (unsigned)q0b;

        float dmin = wave_fmin(hd);
        unsigned cand = (hd == dmin) ? hj : 0xFFFFFFFFu;
        unsigned jmin = wave_umin(cand);

        if (lane == k)
            res = __longlong_as_double((long long)(
                ((unsigned long long)__float_as_uint(dmin) << 32) | jmin));

        if (hd == dmin && hj == jmin) {   // exactly one lane (j unique)
            q0 = q1; q1 = q2; q2 = KEMPTY;
            if (__double_as_longlong(q0) == __double_as_longlong(KEMPTY)) {
                // refill with 3 smallest keys > g (monotone pops -> exact)
                double g = __longlong_as_double((long long)(
                    ((unsigned long long)__float_as_uint(dmin) << 32) | jmin));
                #pragma unroll
                for (int s = 0; s < 32; ++s) {
                    double kk = make_key(dloc[s], s*64 + lane);
                    if (!(kk > g)) kk = KEMPTY;
                    ins3(q0, q1, q2, kk);
                }
            }
        }
    }

    if (lane < KK) {
        const size_t rb = (size_t)row * KK;
        unsigned long long gk = (unsigned long long)__double_as_longlong(res);
        int j = (int)(unsigned)gk;
        float dwin = __uint_as_float((unsigned)(gk >> 32));
        wsEidx[rb + lane] = j;
        wsDnb[rb + lane]  = dwin;
        outEidxF[rb + lane] = (float)j;
    }
}

// ---------------------------------------------------------------------------
// Kernel C: node path
// ---------------------------------------------------------------------------
__global__ __launch_bounds__(128) void node_kernel(
    const float* __restrict__ wsV6,
    const float* __restrict__ nlw, const float* __restrict__ nlb,
    const float* __restrict__ new_, const float* __restrict__ neb,
    const float* __restrict__ nng, const float* __restrict__ nnb,
    float* __restrict__ outV)
{
    int f = threadIdx.x;
    __shared__ float h1[128];
    __shared__ float red[2][2];

    float w2[128];
    #pragma unroll
    for (int c = 0; c < 128; ++c) w2[c] = new_[c*128 + f];
    float w1[6];
    #pragma unroll
    for (int c = 0; c < 6; ++c) w1[c] = nlw[c*128 + f];
    float b1v = nlb[f], b2v = neb[f], gv = nng[f], bv = nnb[f];

    for (int gi = 0; gi < 8; ++gi) {
        int row = blockIdx.x*8 + gi;
        float acc = b1v;
        #pragma unroll
        for (int c = 0; c < 6; ++c) acc = fmaf(wsV6[(size_t)row*6 + c], w1[c], acc);
        h1[f] = acc;
        __syncthreads();

        float a2 = b2v;
        #pragma unroll
        for (int c4 = 0; c4 < 32; ++c4) {
            float4 v = *(const float4*)&h1[c4*4];
            a2 = fmaf(v.x, w2[c4*4+0], a2);
            a2 = fmaf(v.y, w2[c4*4+1], a2);
            a2 = fmaf(v.z, w2[c4*4+2], a2);
            a2 = fmaf(v.w, w2[c4*4+3], a2);
        }
        float s = a2, ss = a2*a2;
        #pragma unroll
        for (int off = 32; off; off >>= 1) {
            s  += __shfl_xor(s,  off, 64);
            ss += __shfl_xor(ss, off, 64);
        }
        int wig = f >> 6;
        if ((f & 63) == 0) { red[wig][0] = s; red[wig][1] = ss; }
        __syncthreads();
        float S = red[0][0] + red[1][0], SS = red[0][1] + red[1][1];
        float mu = S * (1.f/128.f);
        float var = SS * (1.f/128.f) - mu*mu;
        float inv = rsqrtf(var + 1e-5f);
        outV[(size_t)row*128 + f] = (a2 - mu)*inv*gv + bv;
        __syncthreads();
    }
}

// ---------------------------------------------------------------------------
// Kernel D: edge MFMA
// ---------------------------------------------------------------------------
__global__ __launch_bounds__(256, 4) void edge_mfma_kernel(
    const float4* __restrict__ wsCa4,
    const int* __restrict__ ridx, const int* __restrict__ chain,
    const int* __restrict__ wsEidx, const float* __restrict__ wsDnb,
    const float* __restrict__ wsO,
    const float* __restrict__ pe_w, const float* __restrict__ pe_b,
    const __hip_bfloat16* __restrict__ wsW1, const __hip_bfloat16* __restrict__ wsW2,
    const float* __restrict__ elb, const float* __restrict__ eeb,
    const float* __restrict__ lng, const float* __restrict__ lnb,
    float* __restrict__ outE)
{
    __shared__ char smem[64*72*2 + 64*136*2];
    short* Ef  = (short*)smem;
    short* h1t = (short*)(smem + 64*72*2);
    float* redS  = (float*)smem;
    float* redSS = (float*)(smem + 512);

    const int tid  = threadIdx.x;
    const int wave = tid >> 6, lane = tid & 63;
    const int wm = wave >> 1, wn = wave & 1;
    const int lr = lane & 15, lk = lane >> 4;

    float b1v[4], b2v[4], gv[4], bv[4];
    #pragma unroll
    for (int nf = 0; nf < 4; ++nf) {
        int col = wn*64 + nf*16 + lr;
        b1v[nf] = elb[col]; b2v[nf] = eeb[col];
        gv[nf]  = lng[col]; bv[nf]  = lnb[col];
    }

    for (int idx = tid; idx < 64*25; idx += 256) {
        int r = idx / 25, c = 39 + idx % 25;
        Ef[r*72 + c] = 0;
    }

    const int E0 = blockIdx.x * 64;

    if (wave == 0) {
        int ge = E0 + lane;
        int row = ge / KK;
        int b = row >> 11;
        int j = wsEidx[ge];
        float oi[9], oj[9];
        #pragma unroll
        for (int m = 0; m < 9; ++m) {
            oi[m] = wsO[(size_t)row*9 + m];
            oj[m] = wsO[((size_t)(b*NN) + j)*9 + m];
        }
        float4 ci = wsCa4[row];
        float4 cj = wsCa4[(size_t)b*NN + j];
        float dx = cj.x-ci.x, dy = cj.y-ci.y, dz = cj.z-ci.z;
        float t0 = oi[0]*dx + oi[1]*dy + oi[2]*dz;
        float t1 = oi[3]*dx + oi[4]*dy + oi[5]*dz;
        float t2 = oi[6]*dx + oi[7]*dy + oi[8]*dz;
        float nr = sqrtf(t0*t0 + t1*t1 + t2*t2);
        float iv = 1.f/(nr + 1e-8f);
        short* ef = &Ef[lane*72];
        ef[32] = f2bf(t0*iv); ef[33] = f2bf(t1*iv); ef[34] = f2bf(t2*iv);
        float R00 = oi[0]*oj[0]+oi[3]*oj[3]+oi[6]*oj[6];
        float R01 = oi[0]*oj[1]+oi[3]*oj[4]+oi[6]*oj[7];
        float R02 = oi[0]*oj[2]+oi[3]*oj[5]+oi[6]*oj[8];
        float R10 = oi[1]*oj[0]+oi[4]*oj[3]+oi[7]*oj[6];
        float R11 = oi[1]*oj[1]+oi[4]*oj[4]+oi[7]*oj[7];
        float R12 = oi[1]*oj[2]+oi[4]*oj[5]+oi[7]*oj[8];
        float R20 = oi[2]*oj[0]+oi[5]*oj[3]+oi[8]*oj[6];
        float R21 = oi[2]*oj[1]+oi[5]*oj[4]+oi[8]*oj[7];
        float R22 = oi[2]*oj[2]+oi[5]*oj[5]+oi[8]*oj[8];
        float mx = 0.5f*sqrtf(fabsf(1.f + R00 - R11 - R22));
        float my = 0.5f*sqrtf(fabsf(1.f - R00 + R11 - R22));
        float mz = 0.5f*sqrtf(fabsf(1.f - R00 - R11 + R22));
        float qx = sgnf(R21 - R12)*mx;
        float qy = sgnf(R02 - R20)*my;
        float qz = sgnf(R10 - R01)*mz;
        float qw = 0.5f*sqrtf(fmaxf(0.f, 1.f + R00 + R11 + R22));
        float qn = sqrtf(qx*qx + qy*qy + qz*qz + qw*qw);
        float qi = 1.f/(qn + 1e-8f);
        ef[35] = f2bf(qx*qi); ef[36] = f2bf(qy*qi);
        ef[37] = f2bf(qz*qi); ef[38] = f2bf(qw*qi);
    } else if (wave == 1) {
        int ge = E0 + lane;
        float dnb = wsDnb[ge];
        short* ef = &Ef[lane*72 + 16];
        #pragma unroll
        for (int m = 0; m < 16; ++m) {
            float mu = 2.f + (20.f/15.f)*(float)m;
            float z = (dnb - mu) * 0.8f;
            ef[m] = f2bf(expf(-z*z));
        }
    } else if (wave == 2) {
        int ge = E0 + lane;
        int row = ge / KK;
        int b = row >> 11;
        int j = wsEidx[ge];
        int ri = ridx[row], rj = ridx[b*NN + j];
        int ch = (chain[row] == chain[b*NN + j]) ? 1 : 0;
        int dd = min(max(ri - rj + MAXREL, 0), 2*MAXREL);
        dd = ch ? dd : (2*MAXREL + 1);
        short* ef = &Ef[lane*72];
        #pragma unroll
        for (int m = 0; m < 16; ++m) ef[m] = f2bf(pe_w[dd*16 + m] + pe_b[m]);
    }
    __syncthreads();

    const bf16x8* W1f = (const bf16x8*)wsW1;
    const bf16x8* W2f = (const bf16x8*)wsW2;

    f32x4 acc[2][4];
    #pragma unroll
    for (int mf = 0; mf < 2; ++mf)
        #pragma unroll
        for (int nf = 0; nf < 4; ++nf)
            acc[mf][nf] = (f32x4){0.f, 0.f, 0.f, 0.f};
    #pragma unroll
    for (int ks = 0; ks < 2; ++ks) {
        bf16x8 a0 = *(const bf16x8*)&Ef[(wm*32      + lr)*72 + ks*32 + lk*8];
        bf16x8 a1 = *(const bf16x8*)&Ef[(wm*32 + 16 + lr)*72 + ks*32 + lk*8];
        #pragma unroll
        for (int nf = 0; nf < 4; ++nf) {
            bf16x8 Bf = W1f[((wn*4 + nf)*2 + ks)*64 + lane];
            acc[0][nf] = MFMA16(a0, Bf, acc[0][nf]);
            acc[1][nf] = MFMA16(a1, Bf, acc[1][nf]);
        }
    }
    #pragma unroll
    for (int mf = 0; mf < 2; ++mf)
        #pragma unroll
        for (int nf = 0; nf < 4; ++nf)
            #pragma unroll
            for (int r = 0; r < 4; ++r) {
                int row = wm*32 + mf*16 + lk*4 + r;
                int col = wn*64 + nf*16 + lr;
                h1t[row*136 + col] = f2bf(acc[mf][nf][r] + b1v[nf]);
            }
    __syncthreads();

    f32x4 acc2[2][4];
    #pragma unroll
    for (int mf = 0; mf < 2; ++mf)
        #pragma unroll
        for (int nf = 0; nf < 4; ++nf)
            acc2[mf][nf] = (f32x4){0.f, 0.f, 0.f, 0.f};
    #pragma unroll
    for (int ks = 0; ks < 4; ++ks) {
        bf16x8 a0 = *(const bf16x8*)&h1t[(wm*32      + lr)*136 + ks*32 + lk*8];
        bf16x8 a1 = *(const bf16x8*)&h1t[(wm*32 + 16 + lr)*136 + ks*32 + lk*8];
        #pragma unroll
        for (int nf = 0; nf < 4; ++nf) {
            bf16x8 Bf = W2f[((wn*4 + nf)*4 + ks)*64 + lane];
            acc2[0][nf] = MFMA16(a0, Bf, acc2[0][nf]);
            acc2[1][nf] = MFMA16(a1, Bf, acc2[1][nf]);
        }
    }
    #pragma unroll
    for (int mf = 0; mf < 2; ++mf)
        #pragma unroll
        for (int nf = 0; nf < 4; ++nf)
            #pragma unroll
            for (int r = 0; r < 4; ++r)
                acc2[mf][nf][r] += b2v[nf];

    #pragma unroll
    for (int mf = 0; mf < 2; ++mf) {
        #pragma unroll
        for (int r = 0; r < 4; ++r) {
            float v0 = acc2[mf][0][r], v1 = acc2[mf][1][r];
            float v2 = acc2[mf][2][r], v3 = acc2[mf][3][r];
            float s = v0 + v1 + v2 + v3;
            float q = v0*v0 + v1*v1 + v2*v2 + v3*v3;
            #pragma unroll
            for (int off = 1; off < 16; off <<= 1) {
                s += __shfl_xor(s, off, 64);
                q += __shfl_xor(q, off, 64);
            }
            if (lr == 0) {
                int row = wm*32 + mf*16 + lk*4 + r;
                redS[row*2 + wn] = s; redSS[row*2 + wn] = q;
            }
        }
    }
    __syncthreads();

    const size_t obase = (size_t)E0 * 128;
    #pragma unroll
    for (int mf = 0; mf < 2; ++mf) {
        #pragma unroll
        for (int r = 0; r < 4; ++r) {
            int row = wm*32 + mf*16 + lk*4 + r;
            float S = redS[row*2 + 0] + redS[row*2 + 1];
            float Q = redSS[row*2 + 0] + redSS[row*2 + 1];
            float mu = S * (1.f/128.f);
            float var = Q * (1.f/128.f) - mu*mu;
            float inv = rsqrtf(var + 1e-5f);
            #pragma unroll
            for (int nf = 0; nf < 4; ++nf) {
                int col = wn*64 + nf*16 + lr;
                outE[obase + (size_t)row*128 + col] =
                    (acc2[mf][nf][r] - mu)*inv*gv[nf] + bv[nf];
            }
        }
    }
}

// ---------------------------------------------------------------------------
extern "C" void kernel_launch(void* const* d_in, const int* in_sizes, int n_in,
                              void* d_out, int out_size, void* d_ws, size_t ws_size,
                              hipStream_t stream)
{
    const float* X     = (const float*)d_in[0];
    const float* mask  = (const float*)d_in[1];
    const int*   ridx  = (const int*)  d_in[2];
    const int*   chain = (const int*)  d_in[3];
    const float* pe_w  = (const float*)d_in[4];
    const float* pe_b  = (const float*)d_in[5];
    const float* nlw   = (const float*)d_in[6];
    const float* nlb   = (const float*)d_in[7];
    const float* new_  = (const float*)d_in[8];
    const float* neb   = (const float*)d_in[9];
    const float* elw   = (const float*)d_in[10];
    const float* elb   = (const float*)d_in[11];
    const float* eew   = (const float*)d_in[12];
    const float* eeb   = (const float*)d_in[13];
    const float* nng   = (const float*)d_in[14];
    const float* nnb   = (const float*)d_in[15];
    const float* neg_  = (const float*)d_in[16];
    const float* neb_  = (const float*)d_in[17];

    float* out = (float*)d_out;
    char*  ws  = (char*)d_ws;
    int*    wsEidx = (int*)   (ws + WS_EIDX_OFF);
    float*  wsDnb  = (float*) (ws + WS_DNB_OFF);
    float*  wsO    = (float*) (ws + WS_O_OFF);
    float*  wsV6   = (float*) (ws + WS_V6_OFF);
    float4* wsCa4  = (float4*)(ws + WS_CA4_OFF);
    __hip_bfloat16* wsW1 = (__hip_bfloat16*)(ws + WS_W1_OFF);
    __hip_bfloat16* wsW2 = (__hip_bfloat16*)(ws + WS_W2_OFF);

    prep_kernel<<<96, 256, 0, stream>>>(elw, eew, wsW1, wsW2);
    geom_kernel<<<(BB*NN + 255)/256, 256, 0, stream>>>(X, mask, wsO, wsV6, wsCa4);
    topk_kernel<<<BB*NN/4, 256, 0, stream>>>(wsCa4, wsEidx, wsDnb, out + EIDX_OUT_OFF);
    node_kernel<<<BB*NN/8, 128, 0, stream>>>(wsV6, nlw, nlb, new_, neb, nng, nnb, out);
    edge_mfma_kernel<<<BB*NN*KK/64, 256, 0, stream>>>(wsCa4, ridx, chain, wsEidx, wsDnb, wsO,
                                                      pe_w, pe_b, wsW1, wsW2,
                                                      elb, eeb, neg_, neb_, out + E_OUT_OFF);
}